// Round 16
// baseline (171.687 us; speedup 1.0000x reference)
//
#include <hip/hip_runtime.h>
#include <hip/hip_bf16.h>
#include <stdint.h>

#define B_ 4
#define S_ 2048
#define E_ 1024
#define H_ 16
#define D_ 64
#define BS_ (B_*S_)     // 8192
#define N1_ (3*E_)      // 3072

typedef __attribute__((ext_vector_type(4))) float f32x4;
typedef __attribute__((ext_vector_type(16))) float f32x16;
typedef __attribute__((ext_vector_type(8))) short bf16x8;

#define QSCL 0.18033688011112043f   // 0.125 * log2(e), folded into Q at gemm1

__device__ __forceinline__ float expraw(float x) {   // 2^x, no OCML fixup
  float r;
  asm("v_exp_f32 %0, %1" : "=v"(r) : "v"(x));
  return r;
}

__device__ __forceinline__ unsigned short f2bf(float f) {
  union { float f; unsigned u; } v; v.f = f;
  unsigned r = v.u + 0x7fffu + ((v.u >> 16) & 1u);  // RNE
  return (unsigned short)(r >> 16);
}

__device__ __forceinline__ void gload_lds16(const void* g, void* l) {
  __builtin_amdgcn_global_load_lds(
      (const __attribute__((address_space(1))) void*)g,
      (__attribute__((address_space(3))) void*)l, 16, 0, 0);
}

// ---------------- x: f32 -> bf16, vectorized ----------------
__global__ void k_cvt_x(const float* __restrict__ in, unsigned short* __restrict__ out, int n4) {
  int i = blockIdx.x * blockDim.x + threadIdx.x;
  int stride = gridDim.x * blockDim.x;
  for (; i < n4; i += stride) {
    float4 v = ((const float4*)in)[i];
    ushort4 o;
    o.x = f2bf(v.x); o.y = f2bf(v.y); o.z = f2bf(v.z); o.w = f2bf(v.w);
    ((ushort4*)out)[i] = o;
  }
}

// ---------- Wq/Wk/Wv [H][E][D] -> Wt [3*E][E] (B^T layout, bf16) ----------
__global__ void k_wqkv_t(const float* __restrict__ Wq, const float* __restrict__ Wk,
                         const float* __restrict__ Wv, unsigned short* __restrict__ Wt) {
  __shared__ float t[64][65];
  const int et = blockIdx.x, h = blockIdx.y, qkv = blockIdx.z;
  const float* W = (qkv == 0) ? Wq : ((qkv == 1) ? Wk : Wv);
  const int tid = threadIdx.x;
  const int e0 = et * 64;
#pragma unroll
  for (int i = 0; i < 16; ++i) {
    int idx = tid + i * 256;
    int r = idx >> 6, c = idx & 63;
    t[r][c] = W[(size_t)(h * E_ + e0 + r) * D_ + c];
  }
  __syncthreads();
#pragma unroll
  for (int i = 0; i < 16; ++i) {
    int idx = tid + i * 256;
    int d = idx >> 6, j = idx & 63;
    Wt[(size_t)(qkv * E_ + h * D_ + d) * E_ + e0 + j] = f2bf(t[j][d]);
  }
}

// ---------- Wp [E][E] -> Wpt [n][e] bf16 ----------
__global__ void k_wp_t(const float* __restrict__ Wp, unsigned short* __restrict__ Wpt) {
  __shared__ float t[64][65];
  const int ntb = blockIdx.x, etb = blockIdx.y;
  const int tid = threadIdx.x;
  const int n0 = ntb * 64, e0 = etb * 64;
#pragma unroll
  for (int i = 0; i < 16; ++i) {
    int idx = tid + i * 256;
    int r = idx >> 6, c = idx & 63;
    t[r][c] = Wp[(size_t)(e0 + r) * E_ + n0 + c];
  }
  __syncthreads();
#pragma unroll
  for (int i = 0; i < 16; ++i) {
    int idx = tid + i * 256;
    int d = idx >> 6, j = idx & 63;
    Wpt[(size_t)(n0 + d) * E_ + e0 + j] = f2bf(t[j][d]);
  }
}

// ---------- 128x128 bf16 GEMM, counted-vmcnt + swizzled LDS (R11/R12) ----------
// EPI=0 V-column blocks (col0 >= 2E) write TRANSPOSED to Vt (fused vtrans).
// Q cols scaled by QSCL; K cols plain -> O1.
template <int EPI>
__global__ __launch_bounds__(256, 3) void k_gemm_bt(
    const unsigned short* __restrict__ A,   // [M][K] bf16
    const unsigned short* __restrict__ Bt,  // [N][K] bf16
    void* __restrict__ Cv,
    unsigned short* __restrict__ Vtp,       // Vt [64*64][2048] (EPI=0 only)
    const float* __restrict__ bias,
    int M, int N, int K) {
  __shared__ __align__(16) short lA[2][128 * 32];
  __shared__ __align__(16) short lB[2][128 * 32];
  const int tid = threadIdx.x;
  const int lane = tid & 63, wid = tid >> 6;
  const int l16 = lane & 15, l4 = lane >> 4;
  const int row0 = blockIdx.x * 128, col0 = blockIdx.y * 128;
  const int wr = (wid >> 1) * 64, wc = (wid & 1) * 64;

  f32x4 acc[4][4] = {};

  const int cA = tid, cB = tid + 256;   // 16B-chunk ids (512 per tile)
  // inverse-swizzled global source: chunk c holds kchunk (c&3)^((c>>3)&3)
  const size_t ga0 = (size_t)(row0 + (cA >> 2)) * K + (((cA & 3) ^ ((cA >> 3) & 3)) * 8);
  const size_t ga1 = (size_t)(row0 + (cB >> 2)) * K + (((cB & 3) ^ ((cB >> 3) & 3)) * 8);
  const size_t gb0 = (size_t)(col0 + (cA >> 2)) * K + (((cA & 3) ^ ((cA >> 3) & 3)) * 8);
  const size_t gb1 = (size_t)(col0 + (cB >> 2)) * K + (((cB & 3) ^ ((cB >> 3) & 3)) * 8);

#define STAGE2(buf_, k0_)                                  \
  do {                                                     \
    gload_lds16(A + ga0 + (k0_), &lA[buf_][cA * 8]);       \
    gload_lds16(A + ga1 + (k0_), &lA[buf_][cB * 8]);       \
    gload_lds16(Bt + gb0 + (k0_), &lB[buf_][cA * 8]);      \
    gload_lds16(Bt + gb1 + (k0_), &lB[buf_][cB * 8]);      \
  } while (0)

  const int NT = K >> 5;
  STAGE2(0, 0);
  STAGE2(1, 32);

  const int rsw = (l4 ^ ((l16 >> 1) & 3)) * 8;   // swizzled 16B slot (shorts)

  for (int t = 0; t < NT; ++t) {
    const int cur = t & 1;
    if (t < NT - 1) { asm volatile("s_waitcnt vmcnt(4)" ::: "memory"); }
    else            { asm volatile("s_waitcnt vmcnt(0)" ::: "memory"); }
    __builtin_amdgcn_s_barrier();                // all waves' tile-t loads landed
    __builtin_amdgcn_sched_barrier(0);
    bf16x8 af[4], bfv[4];
#pragma unroll
    for (int g = 0; g < 4; ++g)
      af[g] = *(const bf16x8*)&lA[cur][(wr + g * 16 + l16) * 32 + rsw];
#pragma unroll
    for (int g = 0; g < 4; ++g)
      bfv[g] = *(const bf16x8*)&lB[cur][(wc + g * 16 + l16) * 32 + rsw];
    asm volatile("s_waitcnt lgkmcnt(0)" ::: "memory");   // my reads complete
    __builtin_amdgcn_sched_barrier(0);
    __builtin_amdgcn_s_barrier();                // everyone's reads complete
    if (t + 2 < NT) STAGE2(cur, (t + 2) * 32);   // refill; flies under MFMA
#pragma unroll
    for (int i = 0; i < 4; ++i)
#pragma unroll
      for (int j = 0; j < 4; ++j)
        acc[i][j] = __builtin_amdgcn_mfma_f32_16x16x32_bf16(af[i], bfv[j], acc[i][j], 0, 0, 0);
  }
#undef STAGE2

  if (EPI == 0 && col0 >= 2 * E_) {
    // V block: write transposed straight to Vt[(b*1024 + gc-2048)][s]
#pragma unroll
    for (int i = 0; i < 4; ++i) {
#pragma unroll
      for (int j = 0; j < 4; ++j) {
        const int gr = row0 + wr + i * 16 + l4 * 4;   // = b*2048 + s (4-aligned)
        const int gc = col0 + wc + j * 16 + l16;
        const int vrow = (gr >> 11) * 1024 + (gc - 2 * E_);
        const int s = gr & 2047;
#pragma unroll
        for (int r = 0; r < 4; ++r)
          Vtp[(size_t)vrow * S_ + s + r] = f2bf(acc[i][j][r]);
      }
    }
    return;
  }

  const float qs = (EPI == 0 && col0 < E_) ? QSCL : 1.0f;
#pragma unroll
  for (int i = 0; i < 4; ++i) {
#pragma unroll
    for (int j = 0; j < 4; ++j) {
      const int gr = row0 + wr + i * 16 + l4 * 4;
      const int gc = col0 + wc + j * 16 + l16;
      if (EPI == 0) {
        unsigned short* C = (unsigned short*)Cv;
#pragma unroll
        for (int r = 0; r < 4; ++r)
          C[(size_t)(gr + r) * N + gc] = f2bf(acc[i][j][r] * qs);
      } else {
        float* C = (float*)Cv;
        const float bv = bias[gc];
#pragma unroll
        for (int r = 0; r < 4; ++r)
          C[(size_t)(gr + r) * N + gc] = acc[i][j][r] + bv;
      }
    }
  }
}

#define CVTPK(d, a, b) asm("v_cvt_pk_bf16_f32 %0, %1, %2" : "=v"(d) : "v"(a), "v"(b))
#define PLSWAP(x, y)   asm("v_permlane32_swap_b32 %0, %1" : "+v"(x), "+v"(y))

// ---------- fused causal flash attention, swapped-QK 32x32x16 (R14 + occ4) ----------
// R16: single variable vs R14 -> __launch_bounds__(256,4). Grid 1024 = exactly
// 4 blocks/CU ALL-RESIDENT (zero dispatch rounds) + 16 waves/CU latency hiding.
// VGPR 76 < 128-cap, LDS 4x33.3 = 133KB < 160. Everything else R14-exact.
__global__ __launch_bounds__(256, 4) void k_attn(
    const unsigned short* __restrict__ O1,  // [8192][3072]: Q|K|- (Q pre-scaled)
    const unsigned short* __restrict__ Vt,  // [64*64][2048]
    unsigned short* __restrict__ ctx) {     // [8192][1024]
  __shared__ __align__(16) short lK[2][64 * 64];   // XOR-swizzled, rows=kv
  __shared__ __align__(16) short lV[2][64 * 64];   // XOR-swizzled, rows=d
  __shared__ float lRS[4][32];

  const int idx = blockIdx.x;
  const int qi = 15 - (idx >> 6);     // heavy blocks dispatched first
  const int bh = idx & 63;
  const int b = bh >> 4, h = bh & 15;
  const int tid = threadIdx.x, wid = tid >> 6, lane = tid & 63;
  const int l31 = lane & 31, hi = lane >> 5;
  const int q0w = qi * 128 + wid * 32;

  bf16x8 qf[4];
#pragma unroll
  for (int s = 0; s < 4; ++s)
    qf[s] = *(const bf16x8*)&O1[(size_t)(b * S_ + q0w + l31) * N1_ + h * 64 + s * 16 + hi * 8];

  f32x16 acc[2] = {};
  float psum = 0.f;

  const int c0 = tid, c1 = tid + 256;
  const int r0c = c0 >> 3, o0c = (c0 & 7) * 8;
  const int r1c = c1 >> 3, o1c = (c1 & 7) * 8;
  const int ls0 = (r0c * 64 + o0c) ^ ((r0c & 7) << 3);
  const int ls1 = (r1c * 64 + o1c) ^ ((r1c & 7) << 3);

  const unsigned short* Kbase = O1 + (size_t)(b * S_) * N1_ + E_ + h * 64;
  const unsigned short* Vbase = Vt + (size_t)(bh * 64) * S_;

  const int ntiles = qi * 2 + 2;
  bf16x8 krA = *(const bf16x8*)&Kbase[(size_t)r0c * N1_ + o0c];
  bf16x8 krB = *(const bf16x8*)&Kbase[(size_t)r1c * N1_ + o1c];
  bf16x8 vrA = *(const bf16x8*)&Vbase[(size_t)r0c * S_ + o0c];
  bf16x8 vrB = *(const bf16x8*)&Vbase[(size_t)r1c * S_ + o1c];

  for (int t = 0; t < ntiles; ++t) {
    const int cur = t & 1;
    const int kv0 = t * 64;
    *(bf16x8*)&lK[cur][ls0] = krA;
    *(bf16x8*)&lK[cur][ls1] = krB;
    *(bf16x8*)&lV[cur][ls0] = vrA;
    *(bf16x8*)&lV[cur][ls1] = vrB;
    __syncthreads();
    if (t + 1 < ntiles) {           // async-split prefetch: consumed at next
      const int kn = kv0 + 64;      // tile's ds_write -> hides under compute
      krA = *(const bf16x8*)&Kbase[(size_t)(kn + r0c) * N1_ + o0c];
      krB = *(const bf16x8*)&Kbase[(size_t)(kn + r1c) * N1_ + o1c];
      vrA = *(const bf16x8*)&Vbase[(size_t)r0c * S_ + kn + o0c];
      vrB = *(const bf16x8*)&Vbase[(size_t)r1c * S_ + kn + o1c];
    }

    if (kv0 <= q0w + 31) {
      __builtin_amdgcn_s_setprio(1);
      f32x16 s0 = {}, s1 = {};
#pragma unroll
      for (int s = 0; s < 4; ++s) {
        bf16x8 kf0 = *(const bf16x8*)&lK[cur][((l31) * 64 + s * 16 + hi * 8) ^ ((l31 & 7) << 3)];
        s0 = __builtin_amdgcn_mfma_f32_32x32x16_bf16(kf0, qf[s], s0, 0, 0, 0);
        bf16x8 kf1 = *(const bf16x8*)&lK[cur][((32 + l31) * 64 + s * 16 + hi * 8) ^ ((l31 & 7) << 3)];
        s1 = __builtin_amdgcn_mfma_f32_32x32x16_bf16(kf1, qf[s], s1, 0, 0, 0);
      }
      if (kv0 + 63 > q0w) {
        const int qg = q0w + l31;
#pragma unroll
        for (int r = 0; r < 16; ++r) {
          const int kv = kv0 + (r & 3) + 8 * (r >> 2) + 4 * hi;
          if (kv > qg) s0[r] = -1e30f;
          if (kv + 32 > qg) s1[r] = -1e30f;
        }
      }
#pragma unroll
      for (int r = 0; r < 16; ++r) {
        s0[r] = expraw(s0[r]);
        s1[r] = expraw(s1[r]);
        psum += s0[r] + s1[r];
      }
#pragma unroll
      for (int hh = 0; hh < 2; ++hh) {
        unsigned w0, w1, w2, w3, u0, u1, u2, u3;
        if (hh == 0) {
          CVTPK(w0, s0[0], s0[1]);  CVTPK(w2, s0[4], s0[5]);
          CVTPK(w1, s0[2], s0[3]);  CVTPK(w3, s0[6], s0[7]);
          CVTPK(u0, s0[8], s0[9]);  CVTPK(u2, s0[12], s0[13]);
          CVTPK(u1, s0[10], s0[11]); CVTPK(u3, s0[14], s0[15]);
        } else {
          CVTPK(w0, s1[0], s1[1]);  CVTPK(w2, s1[4], s1[5]);
          CVTPK(w1, s1[2], s1[3]);  CVTPK(w3, s1[6], s1[7]);
          CVTPK(u0, s1[8], s1[9]);  CVTPK(u2, s1[12], s1[13]);
          CVTPK(u1, s1[10], s1[11]); CVTPK(u3, s1[14], s1[15]);
        }
        PLSWAP(w0, w2); PLSWAP(w1, w3); PLSWAP(u0, u2); PLSWAP(u1, u3);
        union { unsigned w[4]; bf16x8 v; } paA, paB;
        paA.w[0] = w0; paA.w[1] = w1; paA.w[2] = w2; paA.w[3] = w3;
        paB.w[0] = u0; paB.w[1] = u1; paB.w[2] = u2; paB.w[3] = u3;
#pragma unroll
        for (int g = 0; g < 2; ++g) {
          bf16x8 vfA = *(const bf16x8*)&lV[cur][((g * 32 + l31) * 64 + hh * 32 + hi * 8) ^ ((l31 & 7) << 3)];
          acc[g] = __builtin_amdgcn_mfma_f32_32x32x16_bf16(paA.v, vfA, acc[g], 0, 0, 0);
          bf16x8 vfB = *(const bf16x8*)&lV[cur][((g * 32 + l31) * 64 + hh * 32 + 16 + hi * 8) ^ ((l31 & 7) << 3)];
          acc[g] = __builtin_amdgcn_mfma_f32_32x32x16_bf16(paB.v, vfB, acc[g], 0, 0, 0);
        }
      }
      __builtin_amdgcn_s_setprio(0);
    }
  }

  float rs = psum + __shfl_xor(psum, 32, 64);
  if (lane < 32) lRS[wid][l31] = rs;
  __syncthreads();

#pragma unroll
  for (int r = 0; r < 16; ++r) {
    const int cr = (r & 3) + 8 * (r >> 2) + 4 * hi;
    const float inv = 1.0f / lRS[wid][cr];
    const int q = q0w + cr;
#pragma unroll
    for (int g = 0; g < 2; ++g)
      ctx[(size_t)(b * S_ + q) * E_ + h * 64 + g * 32 + l31] = f2bf(acc[g][r] * inv);
  }
}

extern "C" void kernel_launch(void* const* d_in, const int* in_sizes, int n_in,
                              void* d_out, int out_size, void* d_ws, size_t ws_size,
                              hipStream_t stream) {
  const float* x  = (const float*)d_in[0];
  const float* Wq = (const float*)d_in[1];
  const float* Wk = (const float*)d_in[2];
  const float* Wv = (const float*)d_in[3];
  const float* Wp = (const float*)d_in[4];
  const float* bp = (const float*)d_in[5];
  float* out = (float*)d_out;

  char* ws = (char*)d_ws;
  unsigned short* xb  = (unsigned short*)(ws);             // 16 MiB (reused as ctx)
  unsigned short* Wt  = (unsigned short*)(ws + 16777216);  // 6 MiB
  unsigned short* Wpt = (unsigned short*)(ws + 23068672);  // 2 MiB
  unsigned short* O1  = (unsigned short*)(ws + 25165824);  // 48 MiB (V cols unused)
  unsigned short* Vt  = (unsigned short*)(ws + 75497472);  // 16 MiB
  unsigned short* ctx = xb;  // xb dead after gemm1

  k_cvt_x<<<2048, 256, 0, stream>>>(x, xb, (B_ * S_ * E_) / 4);
  k_wqkv_t<<<dim3(16, 16, 3), 256, 0, stream>>>(Wq, Wk, Wv, Wt);
  k_wp_t<<<dim3(16, 16), 256, 0, stream>>>(Wp, Wpt);
  k_gemm_bt<0><<<dim3(64, 24), 256, 0, stream>>>(xb, Wt, O1, Vt, nullptr, BS_, N1_, E_);
  k_attn<<<dim3(1024), 256, 0, stream>>>(O1, Vt, ctx);
  k_gemm_bt<1><<<dim3(64, 8), 256, 0, stream>>>(ctx, Wpt, out, nullptr, bp, BS_, E_, E_);
}

// Round 17
// 163.600 us; speedup vs baseline: 1.0494x; 1.0494x over previous
//
#include <hip/hip_runtime.h>
#include <hip/hip_bf16.h>
#include <stdint.h>

#define B_ 4
#define S_ 2048
#define E_ 1024
#define H_ 16
#define D_ 64
#define BS_ (B_*S_)     // 8192
#define N1_ (3*E_)      // 3072

typedef __attribute__((ext_vector_type(4))) float f32x4;
typedef __attribute__((ext_vector_type(16))) float f32x16;
typedef __attribute__((ext_vector_type(8))) short bf16x8;

#define QSCL 0.18033688011112043f   // 0.125 * log2(e), folded into Q at gemm1

__device__ __forceinline__ float expraw(float x) {   // 2^x, no OCML fixup
  float r;
  asm("v_exp_f32 %0, %1" : "=v"(r) : "v"(x));
  return r;
}

__device__ __forceinline__ unsigned short f2bf(float f) {
  union { float f; unsigned u; } v; v.f = f;
  unsigned r = v.u + 0x7fffu + ((v.u >> 16) & 1u);  // RNE
  return (unsigned short)(r >> 16);
}

__device__ __forceinline__ void gload_lds16(const void* g, void* l) {
  __builtin_amdgcn_global_load_lds(
      (const __attribute__((address_space(1))) void*)g,
      (__attribute__((address_space(3))) void*)l, 16, 0, 0);
}

// ---------------- x: f32 -> bf16, vectorized ----------------
__global__ void k_cvt_x(const float* __restrict__ in, unsigned short* __restrict__ out, int n4) {
  int i = blockIdx.x * blockDim.x + threadIdx.x;
  int stride = gridDim.x * blockDim.x;
  for (; i < n4; i += stride) {
    float4 v = ((const float4*)in)[i];
    ushort4 o;
    o.x = f2bf(v.x); o.y = f2bf(v.y); o.z = f2bf(v.z); o.w = f2bf(v.w);
    ((ushort4*)out)[i] = o;
  }
}

// ---------- Wq/Wk/Wv [H][E][D] -> Wt [3*E][E] (B^T layout, bf16) ----------
__global__ void k_wqkv_t(const float* __restrict__ Wq, const float* __restrict__ Wk,
                         const float* __restrict__ Wv, unsigned short* __restrict__ Wt) {
  __shared__ float t[64][65];
  const int et = blockIdx.x, h = blockIdx.y, qkv = blockIdx.z;
  const float* W = (qkv == 0) ? Wq : ((qkv == 1) ? Wk : Wv);
  const int tid = threadIdx.x;
  const int e0 = et * 64;
#pragma unroll
  for (int i = 0; i < 16; ++i) {
    int idx = tid + i * 256;
    int r = idx >> 6, c = idx & 63;
    t[r][c] = W[(size_t)(h * E_ + e0 + r) * D_ + c];
  }
  __syncthreads();
#pragma unroll
  for (int i = 0; i < 16; ++i) {
    int idx = tid + i * 256;
    int d = idx >> 6, j = idx & 63;
    Wt[(size_t)(qkv * E_ + h * D_ + d) * E_ + e0 + j] = f2bf(t[j][d]);
  }
}

// ---------- Wp [E][E] -> Wpt [n][e] bf16 ----------
__global__ void k_wp_t(const float* __restrict__ Wp, unsigned short* __restrict__ Wpt) {
  __shared__ float t[64][65];
  const int ntb = blockIdx.x, etb = blockIdx.y;
  const int tid = threadIdx.x;
  const int n0 = ntb * 64, e0 = etb * 64;
#pragma unroll
  for (int i = 0; i < 16; ++i) {
    int idx = tid + i * 256;
    int r = idx >> 6, c = idx & 63;
    t[r][c] = Wp[(size_t)(e0 + r) * E_ + n0 + c];
  }
  __syncthreads();
#pragma unroll
  for (int i = 0; i < 16; ++i) {
    int idx = tid + i * 256;
    int d = idx >> 6, j = idx & 63;
    Wpt[(size_t)(n0 + d) * E_ + e0 + j] = f2bf(t[j][d]);
  }
}

// ---------- 128x128 bf16 GEMM, counted-vmcnt + swizzled LDS (R11/R12) ----------
// R17: 1-D grid + XCD-chunked bijective block swizzle (T1): blocks sharing a
// B-panel land on the same XCD's L2 (B fetched once/XCD; A is L3-resident).
// nwg % 8 == 0 for both gemms (1536 / 512) -> bijection exact.
// EPI=0 V-column blocks (col0 >= 2E) write TRANSPOSED to Vt (fused vtrans).
// Q cols scaled by QSCL; K cols plain -> O1.
template <int EPI>
__global__ __launch_bounds__(256, 3) void k_gemm_bt(
    const unsigned short* __restrict__ A,   // [M][K] bf16
    const unsigned short* __restrict__ Bt,  // [N][K] bf16
    void* __restrict__ Cv,
    unsigned short* __restrict__ Vtp,       // Vt [64*64][2048] (EPI=0 only)
    const float* __restrict__ bias,
    int M, int N, int K) {
  __shared__ __align__(16) short lA[2][128 * 32];
  __shared__ __align__(16) short lB[2][128 * 32];
  const int tid = threadIdx.x;
  const int lane = tid & 63, wid = tid >> 6;
  const int l16 = lane & 15, l4 = lane >> 4;
  // XCD-chunked swizzle: id -> wg, then wg -> (row tile, col tile); M/128 = 64
  const int id = (int)blockIdx.x;
  const int cpx = (int)gridDim.x >> 3;           // nwg % 8 == 0
  const int wg = (id & 7) * cpx + (id >> 3);
  const int row0 = (wg & 63) << 7;
  const int col0 = (wg >> 6) << 7;
  const int wr = (wid >> 1) * 64, wc = (wid & 1) * 64;

  f32x4 acc[4][4] = {};

  const int cA = tid, cB = tid + 256;   // 16B-chunk ids (512 per tile)
  // inverse-swizzled global source: chunk c holds kchunk (c&3)^((c>>3)&3)
  const size_t ga0 = (size_t)(row0 + (cA >> 2)) * K + (((cA & 3) ^ ((cA >> 3) & 3)) * 8);
  const size_t ga1 = (size_t)(row0 + (cB >> 2)) * K + (((cB & 3) ^ ((cB >> 3) & 3)) * 8);
  const size_t gb0 = (size_t)(col0 + (cA >> 2)) * K + (((cA & 3) ^ ((cA >> 3) & 3)) * 8);
  const size_t gb1 = (size_t)(col0 + (cB >> 2)) * K + (((cB & 3) ^ ((cB >> 3) & 3)) * 8);

#define STAGE2(buf_, k0_)                                  \
  do {                                                     \
    gload_lds16(A + ga0 + (k0_), &lA[buf_][cA * 8]);       \
    gload_lds16(A + ga1 + (k0_), &lA[buf_][cB * 8]);       \
    gload_lds16(Bt + gb0 + (k0_), &lB[buf_][cA * 8]);      \
    gload_lds16(Bt + gb1 + (k0_), &lB[buf_][cB * 8]);      \
  } while (0)

  const int NT = K >> 5;
  STAGE2(0, 0);
  STAGE2(1, 32);

  const int rsw = (l4 ^ ((l16 >> 1) & 3)) * 8;   // swizzled 16B slot (shorts)

  for (int t = 0; t < NT; ++t) {
    const int cur = t & 1;
    if (t < NT - 1) { asm volatile("s_waitcnt vmcnt(4)" ::: "memory"); }
    else            { asm volatile("s_waitcnt vmcnt(0)" ::: "memory"); }
    __builtin_amdgcn_s_barrier();                // all waves' tile-t loads landed
    __builtin_amdgcn_sched_barrier(0);
    bf16x8 af[4], bfv[4];
#pragma unroll
    for (int g = 0; g < 4; ++g)
      af[g] = *(const bf16x8*)&lA[cur][(wr + g * 16 + l16) * 32 + rsw];
#pragma unroll
    for (int g = 0; g < 4; ++g)
      bfv[g] = *(const bf16x8*)&lB[cur][(wc + g * 16 + l16) * 32 + rsw];
    asm volatile("s_waitcnt lgkmcnt(0)" ::: "memory");   // my reads complete
    __builtin_amdgcn_sched_barrier(0);
    __builtin_amdgcn_s_barrier();                // everyone's reads complete
    if (t + 2 < NT) STAGE2(cur, (t + 2) * 32);   // refill; flies under MFMA
#pragma unroll
    for (int i = 0; i < 4; ++i)
#pragma unroll
      for (int j = 0; j < 4; ++j)
        acc[i][j] = __builtin_amdgcn_mfma_f32_16x16x32_bf16(af[i], bfv[j], acc[i][j], 0, 0, 0);
  }
#undef STAGE2

  if (EPI == 0 && col0 >= 2 * E_) {
    // V block: write transposed straight to Vt[(b*1024 + gc-2048)][s]
#pragma unroll
    for (int i = 0; i < 4; ++i) {
#pragma unroll
      for (int j = 0; j < 4; ++j) {
        const int gr = row0 + wr + i * 16 + l4 * 4;   // = b*2048 + s (4-aligned)
        const int gc = col0 + wc + j * 16 + l16;
        const int vrow = (gr >> 11) * 1024 + (gc - 2 * E_);
        const int s = gr & 2047;
#pragma unroll
        for (int r = 0; r < 4; ++r)
          Vtp[(size_t)vrow * S_ + s + r] = f2bf(acc[i][j][r]);
      }
    }
    return;
  }

  const float qs = (EPI == 0 && col0 < E_) ? QSCL : 1.0f;
#pragma unroll
  for (int i = 0; i < 4; ++i) {
#pragma unroll
    for (int j = 0; j < 4; ++j) {
      const int gr = row0 + wr + i * 16 + l4 * 4;
      const int gc = col0 + wc + j * 16 + l16;
      if (EPI == 0) {
        unsigned short* C = (unsigned short*)Cv;
#pragma unroll
        for (int r = 0; r < 4; ++r)
          C[(size_t)(gr + r) * N + gc] = f2bf(acc[i][j][r] * qs);
      } else {
        float* C = (float*)Cv;
        const float bv = bias[gc];
#pragma unroll
        for (int r = 0; r < 4; ++r)
          C[(size_t)(gr + r) * N + gc] = acc[i][j][r] + bv;
      }
    }
  }
}

#define CVTPK(d, a, b) asm("v_cvt_pk_bf16_f32 %0, %1, %2" : "=v"(d) : "v"(a), "v"(b))
#define PLSWAP(x, y)   asm("v_permlane32_swap_b32 %0, %1" : "+v"(x), "+v"(y))

// ---------- fused causal flash attention, swapped-QK 32x32x16 (R14-exact) ----------
__global__ __launch_bounds__(256, 3) void k_attn(
    const unsigned short* __restrict__ O1,  // [8192][3072]: Q|K|- (Q pre-scaled)
    const unsigned short* __restrict__ Vt,  // [64*64][2048]
    unsigned short* __restrict__ ctx) {     // [8192][1024]
  __shared__ __align__(16) short lK[2][64 * 64];   // XOR-swizzled, rows=kv
  __shared__ __align__(16) short lV[2][64 * 64];   // XOR-swizzled, rows=d
  __shared__ float lRS[4][32];

  const int idx = blockIdx.x;
  const int qi = 15 - (idx >> 6);     // heavy blocks dispatched first
  const int bh = idx & 63;
  const int b = bh >> 4, h = bh & 15;
  const int tid = threadIdx.x, wid = tid >> 6, lane = tid & 63;
  const int l31 = lane & 31, hi = lane >> 5;
  const int q0w = qi * 128 + wid * 32;

  bf16x8 qf[4];
#pragma unroll
  for (int s = 0; s < 4; ++s)
    qf[s] = *(const bf16x8*)&O1[(size_t)(b * S_ + q0w + l31) * N1_ + h * 64 + s * 16 + hi * 8];

  f32x16 acc[2] = {};
  float psum = 0.f;

  const int c0 = tid, c1 = tid + 256;
  const int r0c = c0 >> 3, o0c = (c0 & 7) * 8;
  const int r1c = c1 >> 3, o1c = (c1 & 7) * 8;
  const int ls0 = (r0c * 64 + o0c) ^ ((r0c & 7) << 3);
  const int ls1 = (r1c * 64 + o1c) ^ ((r1c & 7) << 3);

  const unsigned short* Kbase = O1 + (size_t)(b * S_) * N1_ + E_ + h * 64;
  const unsigned short* Vbase = Vt + (size_t)(bh * 64) * S_;

  const int ntiles = qi * 2 + 2;
  bf16x8 krA = *(const bf16x8*)&Kbase[(size_t)r0c * N1_ + o0c];
  bf16x8 krB = *(const bf16x8*)&Kbase[(size_t)r1c * N1_ + o1c];
  bf16x8 vrA = *(const bf16x8*)&Vbase[(size_t)r0c * S_ + o0c];
  bf16x8 vrB = *(const bf16x8*)&Vbase[(size_t)r1c * S_ + o1c];

  for (int t = 0; t < ntiles; ++t) {
    const int cur = t & 1;
    const int kv0 = t * 64;
    *(bf16x8*)&lK[cur][ls0] = krA;
    *(bf16x8*)&lK[cur][ls1] = krB;
    *(bf16x8*)&lV[cur][ls0] = vrA;
    *(bf16x8*)&lV[cur][ls1] = vrB;
    __syncthreads();
    if (t + 1 < ntiles) {           // async-split prefetch: consumed at next
      const int kn = kv0 + 64;      // tile's ds_write -> hides under compute
      krA = *(const bf16x8*)&Kbase[(size_t)(kn + r0c) * N1_ + o0c];
      krB = *(const bf16x8*)&Kbase[(size_t)(kn + r1c) * N1_ + o1c];
      vrA = *(const bf16x8*)&Vbase[(size_t)r0c * S_ + kn + o0c];
      vrB = *(const bf16x8*)&Vbase[(size_t)r1c * S_ + kn + o1c];
    }

    if (kv0 <= q0w + 31) {
      __builtin_amdgcn_s_setprio(1);
      f32x16 s0 = {}, s1 = {};
#pragma unroll
      for (int s = 0; s < 4; ++s) {
        bf16x8 kf0 = *(const bf16x8*)&lK[cur][((l31) * 64 + s * 16 + hi * 8) ^ ((l31 & 7) << 3)];
        s0 = __builtin_amdgcn_mfma_f32_32x32x16_bf16(kf0, qf[s], s0, 0, 0, 0);
        bf16x8 kf1 = *(const bf16x8*)&lK[cur][((32 + l31) * 64 + s * 16 + hi * 8) ^ ((l31 & 7) << 3)];
        s1 = __builtin_amdgcn_mfma_f32_32x32x16_bf16(kf1, qf[s], s1, 0, 0, 0);
      }
      if (kv0 + 63 > q0w) {
        const int qg = q0w + l31;
#pragma unroll
        for (int r = 0; r < 16; ++r) {
          const int kv = kv0 + (r & 3) + 8 * (r >> 2) + 4 * hi;
          if (kv > qg) s0[r] = -1e30f;
          if (kv + 32 > qg) s1[r] = -1e30f;
        }
      }
#pragma unroll
      for (int r = 0; r < 16; ++r) {
        s0[r] = expraw(s0[r]);
        s1[r] = expraw(s1[r]);
        psum += s0[r] + s1[r];
      }
#pragma unroll
      for (int hh = 0; hh < 2; ++hh) {
        unsigned w0, w1, w2, w3, u0, u1, u2, u3;
        if (hh == 0) {
          CVTPK(w0, s0[0], s0[1]);  CVTPK(w2, s0[4], s0[5]);
          CVTPK(w1, s0[2], s0[3]);  CVTPK(w3, s0[6], s0[7]);
          CVTPK(u0, s0[8], s0[9]);  CVTPK(u2, s0[12], s0[13]);
          CVTPK(u1, s0[10], s0[11]); CVTPK(u3, s0[14], s0[15]);
        } else {
          CVTPK(w0, s1[0], s1[1]);  CVTPK(w2, s1[4], s1[5]);
          CVTPK(w1, s1[2], s1[3]);  CVTPK(w3, s1[6], s1[7]);
          CVTPK(u0, s1[8], s1[9]);  CVTPK(u2, s1[12], s1[13]);
          CVTPK(u1, s1[10], s1[11]); CVTPK(u3, s1[14], s1[15]);
        }
        PLSWAP(w0, w2); PLSWAP(w1, w3); PLSWAP(u0, u2); PLSWAP(u1, u3);
        union { unsigned w[4]; bf16x8 v; } paA, paB;
        paA.w[0] = w0; paA.w[1] = w1; paA.w[2] = w2; paA.w[3] = w3;
        paB.w[0] = u0; paB.w[1] = u1; paB.w[2] = u2; paB.w[3] = u3;
#pragma unroll
        for (int g = 0; g < 2; ++g) {
          bf16x8 vfA = *(const bf16x8*)&lV[cur][((g * 32 + l31) * 64 + hh * 32 + hi * 8) ^ ((l31 & 7) << 3)];
          acc[g] = __builtin_amdgcn_mfma_f32_32x32x16_bf16(paA.v, vfA, acc[g], 0, 0, 0);
          bf16x8 vfB = *(const bf16x8*)&lV[cur][((g * 32 + l31) * 64 + hh * 32 + 16 + hi * 8) ^ ((l31 & 7) << 3)];
          acc[g] = __builtin_amdgcn_mfma_f32_32x32x16_bf16(paB.v, vfB, acc[g], 0, 0, 0);
        }
      }
      __builtin_amdgcn_s_setprio(0);
    }
  }

  float rs = psum + __shfl_xor(psum, 32, 64);
  if (lane < 32) lRS[wid][l31] = rs;
  __syncthreads();

#pragma unroll
  for (int r = 0; r < 16; ++r) {
    const int cr = (r & 3) + 8 * (r >> 2) + 4 * hi;
    const float inv = 1.0f / lRS[wid][cr];
    const int q = q0w + cr;
#pragma unroll
    for (int g = 0; g < 2; ++g)
      ctx[(size_t)(b * S_ + q) * E_ + h * 64 + g * 32 + l31] = f2bf(acc[g][r] * inv);
  }
}

extern "C" void kernel_launch(void* const* d_in, const int* in_sizes, int n_in,
                              void* d_out, int out_size, void* d_ws, size_t ws_size,
                              hipStream_t stream) {
  const float* x  = (const float*)d_in[0];
  const float* Wq = (const float*)d_in[1];
  const float* Wk = (const float*)d_in[2];
  const float* Wv = (const float*)d_in[3];
  const float* Wp = (const float*)d_in[4];
  const float* bp = (const float*)d_in[5];
  float* out = (float*)d_out;

  char* ws = (char*)d_ws;
  unsigned short* xb  = (unsigned short*)(ws);             // 16 MiB (reused as ctx)
  unsigned short* Wt  = (unsigned short*)(ws + 16777216);  // 6 MiB
  unsigned short* Wpt = (unsigned short*)(ws + 23068672);  // 2 MiB
  unsigned short* O1  = (unsigned short*)(ws + 25165824);  // 48 MiB (V cols unused)
  unsigned short* Vt  = (unsigned short*)(ws + 75497472);  // 16 MiB
  unsigned short* ctx = xb;  // xb dead after gemm1

  k_cvt_x<<<2048, 256, 0, stream>>>(x, xb, (B_ * S_ * E_) / 4);
  k_wqkv_t<<<dim3(16, 16, 3), 256, 0, stream>>>(Wq, Wk, Wv, Wt);
  k_wp_t<<<dim3(16, 16), 256, 0, stream>>>(Wp, Wpt);
  k_gemm_bt<0><<<dim3(1536), 256, 0, stream>>>(xb, Wt, O1, Vt, nullptr, BS_, N1_, E_);
  k_attn<<<dim3(1024), 256, 0, stream>>>(O1, Vt, ctx);
  k_gemm_bt<1><<<dim3(512), 256, 0, stream>>>(ctx, Wpt, out, nullptr, bp, BS_, E_, E_);
}

// Round 18
// 139.710 us; speedup vs baseline: 1.2289x; 1.1710x over previous
//
#include <hip/hip_runtime.h>
#include <hip/hip_bf16.h>
#include <stdint.h>

#define B_ 4
#define S_ 2048
#define E_ 1024
#define H_ 16
#define D_ 64
#define BS_ (B_*S_)     // 8192
#define N1_ (3*E_)      // 3072

typedef __attribute__((ext_vector_type(4))) float f32x4;
typedef __attribute__((ext_vector_type(16))) float f32x16;
typedef __attribute__((ext_vector_type(8))) short bf16x8;

#define QSCL 0.18033688011112043f   // 0.125 * log2(e), folded into Q at gemm1

__device__ __forceinline__ float expraw(float x) {   // 2^x, no OCML fixup
  float r;
  asm("v_exp_f32 %0, %1" : "=v"(r) : "v"(x));
  return r;
}

__device__ __forceinline__ unsigned short f2bf(float f) {
  union { float f; unsigned u; } v; v.f = f;
  unsigned r = v.u + 0x7fffu + ((v.u >> 16) & 1u);  // RNE
  return (unsigned short)(r >> 16);
}

__device__ __forceinline__ void gload_lds16(const void* g, void* l) {
  __builtin_amdgcn_global_load_lds(
      (const __attribute__((address_space(1))) void*)g,
      (__attribute__((address_space(3))) void*)l, 16, 0, 0);
}

// ---------------- x: f32 -> bf16, vectorized ----------------
__global__ void k_cvt_x(const float* __restrict__ in, unsigned short* __restrict__ out, int n4) {
  int i = blockIdx.x * blockDim.x + threadIdx.x;
  int stride = gridDim.x * blockDim.x;
  for (; i < n4; i += stride) {
    float4 v = ((const float4*)in)[i];
    ushort4 o;
    o.x = f2bf(v.x); o.y = f2bf(v.y); o.z = f2bf(v.z); o.w = f2bf(v.w);
    ((ushort4*)out)[i] = o;
  }
}

// ---------- Wq/Wk/Wv [H][E][D] -> Wt [3*E][E] (B^T layout, bf16) ----------
__global__ void k_wqkv_t(const float* __restrict__ Wq, const float* __restrict__ Wk,
                         const float* __restrict__ Wv, unsigned short* __restrict__ Wt) {
  __shared__ float t[64][65];
  const int et = blockIdx.x, h = blockIdx.y, qkv = blockIdx.z;
  const float* W = (qkv == 0) ? Wq : ((qkv == 1) ? Wk : Wv);
  const int tid = threadIdx.x;
  const int e0 = et * 64;
#pragma unroll
  for (int i = 0; i < 16; ++i) {
    int idx = tid + i * 256;
    int r = idx >> 6, c = idx & 63;
    t[r][c] = W[(size_t)(h * E_ + e0 + r) * D_ + c];
  }
  __syncthreads();
#pragma unroll
  for (int i = 0; i < 16; ++i) {
    int idx = tid + i * 256;
    int d = idx >> 6, j = idx & 63;
    Wt[(size_t)(qkv * E_ + h * D_ + d) * E_ + e0 + j] = f2bf(t[j][d]);
  }
}

// ---------- Wp [E][E] -> Wpt [n][e] bf16 ----------
__global__ void k_wp_t(const float* __restrict__ Wp, unsigned short* __restrict__ Wpt) {
  __shared__ float t[64][65];
  const int ntb = blockIdx.x, etb = blockIdx.y;
  const int tid = threadIdx.x;
  const int n0 = ntb * 64, e0 = etb * 64;
#pragma unroll
  for (int i = 0; i < 16; ++i) {
    int idx = tid + i * 256;
    int r = idx >> 6, c = idx & 63;
    t[r][c] = Wp[(size_t)(e0 + r) * E_ + n0 + c];
  }
  __syncthreads();
#pragma unroll
  for (int i = 0; i < 16; ++i) {
    int idx = tid + i * 256;
    int d = idx >> 6, j = idx & 63;
    Wpt[(size_t)(n0 + d) * E_ + e0 + j] = f2bf(t[j][d]);
  }
}

// ---------- 128x128 bf16 GEMM, BK=64, counted-vmcnt + swizzled LDS (R18) ----------
// R18 vs R14: BK 32 -> 64 (LDS 64KB, 2 blocks/CU -- R11/R12 showed 2 vs 3 is
// neutral here) => barrier/drain events HALVE (32->16 tiles), 32 MFMA per
// barrier-pair. 128B LDS rows, 8 slots: read slot = (ks*4+l4)^(l16&7) -- each
// consecutive-8-lane service group covers all 8 slots (R11-verified model);
// inverse ((c&7)^((c>>3)&7)) on the GLOBAL staging source, LDS dest linear.
// vmcnt(8) steady state. 2D grid (R17 XCD swizzle reverted: FETCH 4x regress).
// EPI=0: V cols (col0>=2E) -> Vt transposed; Q cols scaled QSCL. EPI=1: +bias.
template <int EPI>
__global__ __launch_bounds__(256, 2) void k_gemm_bt(
    const unsigned short* __restrict__ A,   // [M][K] bf16
    const unsigned short* __restrict__ Bt,  // [N][K] bf16
    void* __restrict__ Cv,
    unsigned short* __restrict__ Vtp,       // Vt [64*64][2048] (EPI=0 only)
    const float* __restrict__ bias,
    int M, int N, int K) {
  __shared__ __align__(16) short lA[2][128 * 64];   // 32 KB
  __shared__ __align__(16) short lB[2][128 * 64];   // 32 KB
  const int tid = threadIdx.x;
  const int lane = tid & 63, wid = tid >> 6;
  const int l16 = lane & 15, l4 = lane >> 4;
  const int row0 = blockIdx.x * 128, col0 = blockIdx.y * 128;
  const int wr = (wid >> 1) * 64, wc = (wid & 1) * 64;

  f32x4 acc[4][4] = {};

  // staging: 4 chunks each of A and B per thread; chunk c: row=c>>3, dest
  // slot=c&7 (linear), global kchunk = (c&7)^((c>>3)&7)  [inverse swizzle]
  const int c0 = tid, c1 = tid + 256, c2 = tid + 512, c3 = tid + 768;
#define GOFF(c_) ((size_t)((c_) >> 3) * K + (((c_) & 7) ^ (((c_) >> 3) & 7)) * 8)
  const size_t ga0 = (size_t)row0 * K + GOFF(c0);
  const size_t ga1 = (size_t)row0 * K + GOFF(c1);
  const size_t ga2 = (size_t)row0 * K + GOFF(c2);
  const size_t ga3 = (size_t)row0 * K + GOFF(c3);
  const size_t gb0 = (size_t)col0 * K + GOFF(c0);
  const size_t gb1 = (size_t)col0 * K + GOFF(c1);
  const size_t gb2 = (size_t)col0 * K + GOFF(c2);
  const size_t gb3 = (size_t)col0 * K + GOFF(c3);
#undef GOFF

#define STAGE2(buf_, k0_)                                   \
  do {                                                      \
    gload_lds16(A + ga0 + (k0_), &lA[buf_][c0 * 8]);        \
    gload_lds16(A + ga1 + (k0_), &lA[buf_][c1 * 8]);        \
    gload_lds16(A + ga2 + (k0_), &lA[buf_][c2 * 8]);        \
    gload_lds16(A + ga3 + (k0_), &lA[buf_][c3 * 8]);        \
    gload_lds16(Bt + gb0 + (k0_), &lB[buf_][c0 * 8]);       \
    gload_lds16(Bt + gb1 + (k0_), &lB[buf_][c1 * 8]);       \
    gload_lds16(Bt + gb2 + (k0_), &lB[buf_][c2 * 8]);       \
    gload_lds16(Bt + gb3 + (k0_), &lB[buf_][c3 * 8]);       \
  } while (0)

  const int NT = K >> 6;                     // 16 for K=1024
  STAGE2(0, 0);
  STAGE2(1, 64);

  // read-side swizzled slots for ks=0,1 (row&7 == l16&7 since wr,g*16 are
  // multiples of 8 in the row index)
  const int rs0 = ((0 * 4 + l4) ^ (l16 & 7)) * 8;
  const int rs1 = ((1 * 4 + l4) ^ (l16 & 7)) * 8;

  for (int t = 0; t < NT; ++t) {
    const int cur = t & 1;
    if (t < NT - 1) { asm volatile("s_waitcnt vmcnt(8)" ::: "memory"); }
    else            { asm volatile("s_waitcnt vmcnt(0)" ::: "memory"); }
    __builtin_amdgcn_s_barrier();            // all waves' tile-t loads landed
    __builtin_amdgcn_sched_barrier(0);
    bf16x8 af0[4], bf0[4], af1[4], bf1[4];
#pragma unroll
    for (int g = 0; g < 4; ++g) {
      af0[g] = *(const bf16x8*)&lA[cur][(wr + g * 16 + l16) * 64 + rs0];
      bf0[g] = *(const bf16x8*)&lB[cur][(wc + g * 16 + l16) * 64 + rs0];
      af1[g] = *(const bf16x8*)&lA[cur][(wr + g * 16 + l16) * 64 + rs1];
      bf1[g] = *(const bf16x8*)&lB[cur][(wc + g * 16 + l16) * 64 + rs1];
    }
    asm volatile("s_waitcnt lgkmcnt(0)" ::: "memory");   // my reads complete
    __builtin_amdgcn_sched_barrier(0);
    __builtin_amdgcn_s_barrier();            // everyone's reads complete
    if (t + 2 < NT) STAGE2(cur, (t + 2) * 64);   // refill; flies under MFMA
#pragma unroll
    for (int i = 0; i < 4; ++i)
#pragma unroll
      for (int j = 0; j < 4; ++j)
        acc[i][j] = __builtin_amdgcn_mfma_f32_16x16x32_bf16(af0[i], bf0[j], acc[i][j], 0, 0, 0);
#pragma unroll
    for (int i = 0; i < 4; ++i)
#pragma unroll
      for (int j = 0; j < 4; ++j)
        acc[i][j] = __builtin_amdgcn_mfma_f32_16x16x32_bf16(af1[i], bf1[j], acc[i][j], 0, 0, 0);
  }
#undef STAGE2

  if (EPI == 0 && col0 >= 2 * E_) {
    // V block: write transposed straight to Vt[(b*1024 + gc-2048)][s]
#pragma unroll
    for (int i = 0; i < 4; ++i) {
#pragma unroll
      for (int j = 0; j < 4; ++j) {
        const int gr = row0 + wr + i * 16 + l4 * 4;   // = b*2048 + s (4-aligned)
        const int gc = col0 + wc + j * 16 + l16;
        const int vrow = (gr >> 11) * 1024 + (gc - 2 * E_);
        const int s = gr & 2047;
#pragma unroll
        for (int r = 0; r < 4; ++r)
          Vtp[(size_t)vrow * S_ + s + r] = f2bf(acc[i][j][r]);
      }
    }
    return;
  }

  const float qs = (EPI == 0 && col0 < E_) ? QSCL : 1.0f;
#pragma unroll
  for (int i = 0; i < 4; ++i) {
#pragma unroll
    for (int j = 0; j < 4; ++j) {
      const int gr = row0 + wr + i * 16 + l4 * 4;
      const int gc = col0 + wc + j * 16 + l16;
      if (EPI == 0) {
        unsigned short* C = (unsigned short*)Cv;
#pragma unroll
        for (int r = 0; r < 4; ++r)
          C[(size_t)(gr + r) * N + gc] = f2bf(acc[i][j][r] * qs);
      } else {
        float* C = (float*)Cv;
        const float bv = bias[gc];
#pragma unroll
        for (int r = 0; r < 4; ++r)
          C[(size_t)(gr + r) * N + gc] = acc[i][j][r] + bv;
      }
    }
  }
}

#define CVTPK(d, a, b) asm("v_cvt_pk_bf16_f32 %0, %1, %2" : "=v"(d) : "v"(a), "v"(b))
#define PLSWAP(x, y)   asm("v_permlane32_swap_b32 %0, %1" : "+v"(x), "+v"(y))

// ---------- fused causal flash attention, swapped-QK 32x32x16 (R14-exact) ----------
__global__ __launch_bounds__(256, 3) void k_attn(
    const unsigned short* __restrict__ O1,  // [8192][3072]: Q|K|- (Q pre-scaled)
    const unsigned short* __restrict__ Vt,  // [64*64][2048]
    unsigned short* __restrict__ ctx) {     // [8192][1024]
  __shared__ __align__(16) short lK[2][64 * 64];   // XOR-swizzled, rows=kv
  __shared__ __align__(16) short lV[2][64 * 64];   // XOR-swizzled, rows=d
  __shared__ float lRS[4][32];

  const int idx = blockIdx.x;
  const int qi = 15 - (idx >> 6);     // heavy blocks dispatched first
  const int bh = idx & 63;
  const int b = bh >> 4, h = bh & 15;
  const int tid = threadIdx.x, wid = tid >> 6, lane = tid & 63;
  const int l31 = lane & 31, hi = lane >> 5;
  const int q0w = qi * 128 + wid * 32;

  bf16x8 qf[4];
#pragma unroll
  for (int s = 0; s < 4; ++s)
    qf[s] = *(const bf16x8*)&O1[(size_t)(b * S_ + q0w + l31) * N1_ + h * 64 + s * 16 + hi * 8];

  f32x16 acc[2] = {};
  float psum = 0.f;

  const int c0 = tid, c1 = tid + 256;
  const int r0c = c0 >> 3, o0c = (c0 & 7) * 8;
  const int r1c = c1 >> 3, o1c = (c1 & 7) * 8;
  const int ls0 = (r0c * 64 + o0c) ^ ((r0c & 7) << 3);
  const int ls1 = (r1c * 64 + o1c) ^ ((r1c & 7) << 3);

  const unsigned short* Kbase = O1 + (size_t)(b * S_) * N1_ + E_ + h * 64;
  const unsigned short* Vbase = Vt + (size_t)(bh * 64) * S_;

  const int ntiles = qi * 2 + 2;
  bf16x8 krA = *(const bf16x8*)&Kbase[(size_t)r0c * N1_ + o0c];
  bf16x8 krB = *(const bf16x8*)&Kbase[(size_t)r1c * N1_ + o1c];
  bf16x8 vrA = *(const bf16x8*)&Vbase[(size_t)r0c * S_ + o0c];
  bf16x8 vrB = *(const bf16x8*)&Vbase[(size_t)r1c * S_ + o1c];

  for (int t = 0; t < ntiles; ++t) {
    const int cur = t & 1;
    const int kv0 = t * 64;
    *(bf16x8*)&lK[cur][ls0] = krA;
    *(bf16x8*)&lK[cur][ls1] = krB;
    *(bf16x8*)&lV[cur][ls0] = vrA;
    *(bf16x8*)&lV[cur][ls1] = vrB;
    __syncthreads();
    if (t + 1 < ntiles) {           // async-split prefetch: consumed at next
      const int kn = kv0 + 64;      // tile's ds_write -> hides under compute
      krA = *(const bf16x8*)&Kbase[(size_t)(kn + r0c) * N1_ + o0c];
      krB = *(const bf16x8*)&Kbase[(size_t)(kn + r1c) * N1_ + o1c];
      vrA = *(const bf16x8*)&Vbase[(size_t)r0c * S_ + kn + o0c];
      vrB = *(const bf16x8*)&Vbase[(size_t)r1c * S_ + kn + o1c];
    }

    if (kv0 <= q0w + 31) {
      __builtin_amdgcn_s_setprio(1);
      f32x16 s0 = {}, s1 = {};
#pragma unroll
      for (int s = 0; s < 4; ++s) {
        bf16x8 kf0 = *(const bf16x8*)&lK[cur][((l31) * 64 + s * 16 + hi * 8) ^ ((l31 & 7) << 3)];
        s0 = __builtin_amdgcn_mfma_f32_32x32x16_bf16(kf0, qf[s], s0, 0, 0, 0);
        bf16x8 kf1 = *(const bf16x8*)&lK[cur][((32 + l31) * 64 + s * 16 + hi * 8) ^ ((l31 & 7) << 3)];
        s1 = __builtin_amdgcn_mfma_f32_32x32x16_bf16(kf1, qf[s], s1, 0, 0, 0);
      }
      if (kv0 + 63 > q0w) {
        const int qg = q0w + l31;
#pragma unroll
        for (int r = 0; r < 16; ++r) {
          const int kv = kv0 + (r & 3) + 8 * (r >> 2) + 4 * hi;
          if (kv > qg) s0[r] = -1e30f;
          if (kv + 32 > qg) s1[r] = -1e30f;
        }
      }
#pragma unroll
      for (int r = 0; r < 16; ++r) {
        s0[r] = expraw(s0[r]);
        s1[r] = expraw(s1[r]);
        psum += s0[r] + s1[r];
      }
#pragma unroll
      for (int hh = 0; hh < 2; ++hh) {
        unsigned w0, w1, w2, w3, u0, u1, u2, u3;
        if (hh == 0) {
          CVTPK(w0, s0[0], s0[1]);  CVTPK(w2, s0[4], s0[5]);
          CVTPK(w1, s0[2], s0[3]);  CVTPK(w3, s0[6], s0[7]);
          CVTPK(u0, s0[8], s0[9]);  CVTPK(u2, s0[12], s0[13]);
          CVTPK(u1, s0[10], s0[11]); CVTPK(u3, s0[14], s0[15]);
        } else {
          CVTPK(w0, s1[0], s1[1]);  CVTPK(w2, s1[4], s1[5]);
          CVTPK(w1, s1[2], s1[3]);  CVTPK(w3, s1[6], s1[7]);
          CVTPK(u0, s1[8], s1[9]);  CVTPK(u2, s1[12], s1[13]);
          CVTPK(u1, s1[10], s1[11]); CVTPK(u3, s1[14], s1[15]);
        }
        PLSWAP(w0, w2); PLSWAP(w1, w3); PLSWAP(u0, u2); PLSWAP(u1, u3);
        union { unsigned w[4]; bf16x8 v; } paA, paB;
        paA.w[0] = w0; paA.w[1] = w1; paA.w[2] = w2; paA.w[3] = w3;
        paB.w[0] = u0; paB.w[1] = u1; paB.w[2] = u2; paB.w[3] = u3;
#pragma unroll
        for (int g = 0; g < 2; ++g) {
          bf16x8 vfA = *(const bf16x8*)&lV[cur][((g * 32 + l31) * 64 + hh * 32 + hi * 8) ^ ((l31 & 7) << 3)];
          acc[g] = __builtin_amdgcn_mfma_f32_32x32x16_bf16(paA.v, vfA, acc[g], 0, 0, 0);
          bf16x8 vfB = *(const bf16x8*)&lV[cur][((g * 32 + l31) * 64 + hh * 32 + 16 + hi * 8) ^ ((l31 & 7) << 3)];
          acc[g] = __builtin_amdgcn_mfma_f32_32x32x16_bf16(paB.v, vfB, acc[g], 0, 0, 0);
        }
      }
      __builtin_amdgcn_s_setprio(0);
    }
  }

  float rs = psum + __shfl_xor(psum, 32, 64);
  if (lane < 32) lRS[wid][l31] = rs;
  __syncthreads();

#pragma unroll
  for (int r = 0; r < 16; ++r) {
    const int cr = (r & 3) + 8 * (r >> 2) + 4 * hi;
    const float inv = 1.0f / lRS[wid][cr];
    const int q = q0w + cr;
#pragma unroll
    for (int g = 0; g < 2; ++g)
      ctx[(size_t)(b * S_ + q) * E_ + h * 64 + g * 32 + l31] = f2bf(acc[g][r] * inv);
  }
}

extern "C" void kernel_launch(void* const* d_in, const int* in_sizes, int n_in,
                              void* d_out, int out_size, void* d_ws, size_t ws_size,
                              hipStream_t stream) {
  const float* x  = (const float*)d_in[0];
  const float* Wq = (const float*)d_in[1];
  const float* Wk = (const float*)d_in[2];
  const float* Wv = (const float*)d_in[3];
  const float* Wp = (const float*)d_in[4];
  const float* bp = (const float*)d_in[5];
  float* out = (float*)d_out;

  char* ws = (char*)d_ws;
  unsigned short* xb  = (unsigned short*)(ws);             // 16 MiB (reused as ctx)
  unsigned short* Wt  = (unsigned short*)(ws + 16777216);  // 6 MiB
  unsigned short* Wpt = (unsigned short*)(ws + 23068672);  // 2 MiB
  unsigned short* O1  = (unsigned short*)(ws + 25165824);  // 48 MiB (V cols unused)
  unsigned short* Vt  = (unsigned short*)(ws + 75497472);  // 16 MiB
  unsigned short* ctx = xb;  // xb dead after gemm1

  k_cvt_x<<<2048, 256, 0, stream>>>(x, xb, (B_ * S_ * E_) / 4);
  k_wqkv_t<<<dim3(16, 16, 3), 256, 0, stream>>>(Wq, Wk, Wv, Wt);
  k_wp_t<<<dim3(16, 16), 256, 0, stream>>>(Wp, Wpt);
  k_gemm_bt<0><<<dim3(64, 24), 256, 0, stream>>>(xb, Wt, O1, Vt, nullptr, BS_, N1_, E_);
  k_attn<<<dim3(1024), 256, 0, stream>>>(O1, Vt, ctx);
  k_gemm_bt<1><<<dim3(64, 8), 256, 0, stream>>>(ctx, Wpt, out, nullptr, bp, BS_, E_, E_);
}